// Round 7
// baseline (146.417 us; speedup 1.0000x reference)
//
#include <hip/hip_runtime.h>

// SingleStageDetector, R16 = barrier-free streaming GEMM1.
// R9-R15 post-mortem: six structurally different staged kernels (reg-staged,
// double-buffered, async global_load_lds, 1-4 blocks/CU) ALL pin at ~42.5us;
// no counter (occupancy 17-34%, conflicts 1.4-2.7M, FETCH 33-113MB)
// correlates. The only invariant: a barrier-phased K-loop draining vmcnt
// every chunk -> HBM pipe empty between phases (~2.4 B/cyc/CU effective vs
// 10.25 available; the fill kernel proves 6.5 TB/s with the opposite,
// barrier-free structure).
// Fix: NO F staging, NO K-loop barriers. B-fragments are built directly
// from global F: hw (contiguous, 49 dwords/row) is the fragment lane axis;
// lane reads 8 f32 at stride 49 (16-lane 64B segments, const offsets),
// 4x v_cvt_pk_bf16_f32 -> bf16x8. Every wave issues 18 independent vmem
// instrs per K-step continuously (copy-kernel regime). Each F element read
// exactly once globally (quads=channels, halves=columns partition).
// Block = (half, image), id = half*256+b -> both halves of an image on one
// XCD (id%8 dispatch). 4 waves x 2 m-tiles, acc[2][2]. One barrier total
// (h -> smHT 8.7KB) before GEMM2 (10 tiles) + epilogue + IoU.
// prep_w unchanged: W1/W2 -> fragment-ready bf16 images in ws.

#define CIN_  1280
#define HW_   49
#define HID_  128
#define OUTD_ 65
#define NGT_  40
#define NP_   441

// flat output offsets (elements), reference return order
#define CONF_OFF 0
#define OFFS_OFF 112896   // 256*9*49
#define CLS_OFF  564480   // + 256*9*4*49
#define IOU_OFF  815360   // + 256*20*49 ; total 5,331,200

// ws layout (u32): W1f frags ((K32*8+mt)*64+lane)*4+sub, then W2f frags
#define WS_W1F_U32 81920u
#define WS_W2F_U32 5120u

typedef __bf16 bf16x8 __attribute__((ext_vector_type(8)));
typedef float  f32x4  __attribute__((ext_vector_type(4)));

__device__ __forceinline__ unsigned pack2bf(float lo, float hi) {
    unsigned short a = __builtin_bit_cast(unsigned short, (__bf16)lo);
    unsigned short b = __builtin_bit_cast(unsigned short, (__bf16)hi);
    return (unsigned)a | ((unsigned)b << 16);   // compiler: v_cvt_pk_bf16_f32
}
__device__ __forceinline__ float sigmoidf_(float v) { return 1.f / (1.f + __expf(-v)); }

__device__ __forceinline__ bf16x8 ld_frag(const unsigned* p) {
    union { uint4 u; bf16x8 v; } x;
    x.u = *(const uint4*)p;                       // 16B-aligned ds_read_b128
    return x.v;
}
__device__ __forceinline__ bf16x8 as_bf(uint4 u) {
    union { uint4 u; bf16x8 v; } x; x.u = u; return x.v;
}
// 8 f32 (already in regs) -> bf16x8
__device__ __forceinline__ bf16x8 pack8(const float* v) {
    union { unsigned u[4]; bf16x8 x; } r;
    #pragma unroll
    for (int j = 0; j < 4; ++j) r.u[j] = pack2bf(v[2 * j], v[2 * j + 1]);
    return r.x;
}

// ---------------------------------------------------------------------------
// prep_w: W1 (128,1280) + W2 (65,128) -> fragment-ready bf16 images. (R8.)
// ---------------------------------------------------------------------------
__global__ __launch_bounds__(256) void prep_w(
    const float* __restrict__ W1, const float* __restrict__ W2,
    unsigned* __restrict__ ws)
{
    int X = blockIdx.x * 256 + threadIdx.x;       // 0..87039
    if (X < (int)WS_W1F_U32) {
        int sub = X & 3, lane = (X >> 2) & 63, f = X >> 8;
        int mt = f & 7, K32 = f >> 3;
        int o = mt * 16 + (lane & 15);
        int c = K32 * 32 + (lane >> 4) * 8 + sub * 2;
        float2 v = *(const float2*)(W1 + o * CIN_ + c);
        ws[X] = pack2bf(v.x, v.y);
    } else {
        int Y = X - (int)WS_W1F_U32;              // 0..5119
        int sub = Y & 3, lane = (Y >> 2) & 63, f = Y >> 8;
        int mt2 = f % 5, ks2 = f / 5;
        int o2 = mt2 * 16 + (lane & 15);
        int c = ks2 * 32 + (lane >> 4) * 8 + sub * 2;
        unsigned val = 0;
        if (o2 < OUTD_) {
            float2 v = *(const float2*)(W2 + o2 * HID_ + c);
            val = pack2bf(v.x, v.y);
        }
        ws[WS_W1F_U32 + Y] = val;
    }
}

// ---------------------------------------------------------------------------
// fused_main: block = (half, image): id = half*256 + b (co-XCD halves).
// 256 thr = 4 waves; wave w owns m-tiles 2w, 2w+1; columns = 32 hw
// (half 0: 0-31; half 1: 32-48 + clamped pad). LDS: smHT only (32x68 u32).
// ---------------------------------------------------------------------------
__global__ __launch_bounds__(256, 4) void fused_main(
    const float* __restrict__ F,     // (256,1280,7,7)
    const float* __restrict__ grd,   // (256,7,7,2)
    const float* __restrict__ bbox,  // (256,40,5)
    const float* __restrict__ anc,   // (9,2)
    const unsigned* __restrict__ wsW,
    const float* __restrict__ B1,    // (128,)
    const float* __restrict__ B2,    // (65,)
    float* __restrict__ out)
{
    __shared__ __align__(16) unsigned smHT[32 * 68];   // 8,704 B

    const int tid  = threadIdx.x;
    const int id   = blockIdx.x;
    const int half = id >> 8;          // 0..1
    const int b    = id & 255;         // image
    const int lane = tid & 63;
    const int w    = tid >> 6;         // 0..3
    const int quad = lane >> 4;
    const int m16  = lane & 15;
    const int hw0  = half * 32;

    const float* Fb = F + b * (CIN_ * HW_);
    const int colA = hw0 + m16;                        // nh=0 column (<=47)
    const int colB = min(hw0 + 16 + m16, HW_ - 1);     // nh=1 column, clamped
    const int mt0 = 2 * w, mt1 = 2 * w + 1;
    const uint4* Af = (const uint4*)wsW;

    // per-K-step loads: 8 f32 (stride 49) per column set + 2 A-frag uint4.
    #define LOADK(k, vA, vB, ra0, ra1)                                       \
        {                                                                    \
            const float* pk = Fb + ((k) * 32 + quad * 8) * 49;               \
            _Pragma("unroll")                                                \
            for (int j = 0; j < 8; ++j) {                                    \
                vA[j] = pk[j * 49 + colA];                                   \
                vB[j] = pk[j * 49 + colB];                                   \
            }                                                                \
            ra0 = Af[((k) * 8 + mt0) * 64 + lane];                           \
            ra1 = Af[((k) * 8 + mt1) * 64 + lane];                           \
        }

    // ---- GEMM1: barrier-free 40-step stream, 1-deep software pipeline ----
    f32x4 acc[2][2] = {{(f32x4)(0.f), (f32x4)(0.f)}, {(f32x4)(0.f), (f32x4)(0.f)}};
    float cA[8], cB[8]; uint4 ca0, ca1;
    LOADK(0, cA, cB, ca0, ca1);
    #pragma unroll
    for (int k = 0; k < 40; ++k) {
        float nA[8], nB[8]; uint4 na0, na1;
        if (k < 39) LOADK(k + 1, nA, nB, na0, na1);
        bf16x8 Bf0 = pack8(cA);
        bf16x8 Bf1 = pack8(cB);
        bf16x8 A0 = as_bf(ca0);
        bf16x8 A1 = as_bf(ca1);
        acc[0][0] = __builtin_amdgcn_mfma_f32_16x16x32_bf16(A0, Bf0, acc[0][0], 0, 0, 0);
        acc[0][1] = __builtin_amdgcn_mfma_f32_16x16x32_bf16(A0, Bf1, acc[0][1], 0, 0, 0);
        acc[1][0] = __builtin_amdgcn_mfma_f32_16x16x32_bf16(A1, Bf0, acc[1][0], 0, 0, 0);
        acc[1][1] = __builtin_amdgcn_mfma_f32_16x16x32_bf16(A1, Bf1, acc[1][1], 0, 0, 0);
        if (k < 39) {
            #pragma unroll
            for (int j = 0; j < 8; ++j) { cA[j] = nA[j]; cB[j] = nB[j]; }
            ca0 = na0; ca1 = na1;
        }
    }

    // ---- h: bias + leaky, packed o-pairs -> smHT[row*68 + o/2] ----
    // row = nh*16 + m16 (local hw), o = (2w+mo)*16 + quad*4 + r
    #pragma unroll
    for (int mo = 0; mo < 2; ++mo) {
        #pragma unroll
        for (int nh = 0; nh < 2; ++nh) {
            int row = nh * 16 + m16;
            #pragma unroll
            for (int rp = 0; rp < 2; ++rp) {
                int o0 = (2 * w + mo) * 16 + quad * 4 + 2 * rp;
                float v0 = acc[mo][nh][2 * rp]     + B1[o0];
                float v1 = acc[mo][nh][2 * rp + 1] + B1[o0 + 1];
                v0 = v0 > 0.f ? v0 : 0.01f * v0;
                v1 = v1 > 0.f ? v1 : 0.01f * v1;
                smHT[row * 68 + (o0 >> 1)] = pack2bf(v0, v1);
            }
        }
    }
    __syncthreads();   // the only block-wide barrier

    // ---- GEMM2: 10 tiles (5 o2-tiles x 2 hw-tiles); wave w: T = w, w+4, w+8
    for (int T = w; T < 10; T += 4) {
        int m2 = T % 5, nt2 = T / 5;
        const uint4* A2p = (const uint4*)(wsW + WS_W1F_U32) + m2 * 64 + lane;
        uint4 a20 = A2p[0], a21 = A2p[320], a22 = A2p[640], a23 = A2p[960];
        f32x4 c2 = (f32x4)(0.f);
        const unsigned* Bb = smHT + (nt2 * 16 + m16) * 68 + quad * 4;
        c2 = __builtin_amdgcn_mfma_f32_16x16x32_bf16(as_bf(a20), ld_frag(Bb +  0), c2, 0, 0, 0);
        c2 = __builtin_amdgcn_mfma_f32_16x16x32_bf16(as_bf(a21), ld_frag(Bb + 16), c2, 0, 0, 0);
        c2 = __builtin_amdgcn_mfma_f32_16x16x32_bf16(as_bf(a22), ld_frag(Bb + 32), c2, 0, 0, 0);
        c2 = __builtin_amdgcn_mfma_f32_16x16x32_bf16(as_bf(a23), ld_frag(Bb + 48), c2, 0, 0, 0);
        int hw = hw0 + nt2 * 16 + m16;
        if (hw < HW_) {
            #pragma unroll
            for (int r = 0; r < 4; ++r) {
                int o2 = m2 * 16 + quad * 4 + r;
                if (o2 >= OUTD_) continue;
                float aa = c2[r] + B2[o2];
                unsigned dst; float val;
                if (o2 < 36) {
                    int an9 = o2 >> 2, kk = o2 & 3;
                    val = (kk < 2) ? (sigmoidf_(aa) - 0.5f) : aa;
                    dst = OFFS_OFF + b * 1764 + an9 * 196 + kk * 49 + hw;
                } else if (o2 < 45) {
                    val = sigmoidf_(aa);
                    dst = CONF_OFF + b * 441 + (o2 - 36) * 49 + hw;
                } else {
                    val = aa;
                    dst = CLS_OFF + b * 980 + (o2 - 45) * 49 + hw;
                }
                out[dst] = val;
            }
        }
    }

    // ---- IoU: wave-uniform p, g = lane (<40), coalesced stores ----
    {
        int gl = (lane < NGT_) ? lane : 0;
        const float* gb = bbox + b * 200 + gl * 5;
        float gx1 = gb[0], gy1 = gb[1], gx2 = gb[2], gy2 = gb[3];
        float gA = (gx2 - gx1) * (gy2 - gy1);
        const int pstart = half ? 221 : 0;
        const int pend   = half ? NP_ : 221;
        #pragma unroll 4
        for (int p = pstart + w; p < pend; p += 4) {
            int a9 = p / 49, r = p - a9 * 49;
            float2 ct = *(const float2*)(grd + b * 98 + 2 * r);
            float hx = anc[2 * a9] * 0.5f,  hy = anc[2 * a9 + 1] * 0.5f;
            float px1 = ct.x - hx, py1 = ct.y - hy, px2 = ct.x + hx, py2 = ct.y + hy;
            float pA = (px2 - px1) * (py2 - py1);
            float legal = (fminf(fminf(px1, py1), fminf(px2, py2)) > 0.f) ? 1.f : 0.f;
            float tlx = fmaxf(px1, gx1), tly = fmaxf(py1, gy1);
            float brx = fminf(px2, gx2), bry = fminf(py2, gy2);
            float dx = fmaxf(brx - tlx, 0.f), dy = fmaxf(bry - tly, 0.f);
            float inter = dx * dy * legal;
            float iou = __fdividef(inter, gA + pA - inter);
            if (lane < NGT_)
                out[IOU_OFF + b * (NP_ * NGT_) + p * 40 + lane] = iou;
        }
    }
}

extern "C" void kernel_launch(void* const* d_in, const int* in_sizes, int n_in,
                              void* d_out, int out_size, void* d_ws, size_t ws_size,
                              hipStream_t stream) {
    const float* F  = (const float*)d_in[0];
    const float* G  = (const float*)d_in[1];
    const float* BB = (const float*)d_in[2];
    const float* AN = (const float*)d_in[3];
    const float* W1 = (const float*)d_in[4];
    const float* B1 = (const float*)d_in[5];
    const float* W2 = (const float*)d_in[6];
    const float* B2 = (const float*)d_in[7];
    float* out = (float*)d_out;
    unsigned* wsu = (unsigned*)d_ws;

    prep_w<<<340, 256, 0, stream>>>(W1, W2, wsu);
    fused_main<<<512, 256, 0, stream>>>(F, G, BB, AN, wsu, B1, B2, out);
}